// Round 1
// baseline (1108.760 us; speedup 1.0000x reference)
//
#include <hip/hip_runtime.h>
#include <stdint.h>

typedef _Float16 f16x8 __attribute__((ext_vector_type(8)));
typedef _Float16 f16x4 __attribute__((ext_vector_type(4)));
typedef float    f32x4 __attribute__((ext_vector_type(4)));

// ---------------------------------------------------------------- utilities

__global__ void k_cast(const float* __restrict__ in, _Float16* __restrict__ out, int n) {
    int i = (blockIdx.x * 256 + threadIdx.x) * 4;
    if (i < n) {
        float4 v = *reinterpret_cast<const float4*>(in + i);
        f16x4 o = { (_Float16)v.x, (_Float16)v.y, (_Float16)v.z, (_Float16)v.w };
        *reinterpret_cast<f16x4*>(out + i) = o;
    }
}

// rows of 2048, one block (256 thr) per row; writes f16 and optionally f32
__global__ __launch_bounds__(256) void k_rmsnorm(
    const float* __restrict__ x, const float* __restrict__ w,
    _Float16* __restrict__ oh, float* __restrict__ of)
{
    const int row = blockIdx.x, tid = threadIdx.x;
    const float* xr = x + (size_t)row * 2048;
    float4 a = *reinterpret_cast<const float4*>(xr + tid * 8);
    float4 b = *reinterpret_cast<const float4*>(xr + tid * 8 + 4);
    float ss = a.x*a.x + a.y*a.y + a.z*a.z + a.w*a.w
             + b.x*b.x + b.y*b.y + b.z*b.z + b.w*b.w;
    #pragma unroll
    for (int m = 1; m < 64; m <<= 1) ss += __shfl_xor(ss, m);
    __shared__ float red[4];
    if ((tid & 63) == 0) red[tid >> 6] = ss;
    __syncthreads();
    float tot = red[0] + red[1] + red[2] + red[3];
    float r = rsqrtf(tot * (1.f / 2048.f) + 1e-6f);
    float4 wa = *reinterpret_cast<const float4*>(w + tid * 8);
    float4 wb = *reinterpret_cast<const float4*>(w + tid * 8 + 4);
    float o0 = a.x*r*wa.x, o1 = a.y*r*wa.y, o2 = a.z*r*wa.z, o3 = a.w*r*wa.w;
    float o4 = b.x*r*wb.x, o5 = b.y*r*wb.y, o6 = b.z*r*wb.z, o7 = b.w*r*wb.w;
    f16x8 hv = { (_Float16)o0,(_Float16)o1,(_Float16)o2,(_Float16)o3,
                 (_Float16)o4,(_Float16)o5,(_Float16)o6,(_Float16)o7 };
    *reinterpret_cast<f16x8*>(oh + (size_t)row * 2048 + tid * 8) = hv;
    if (of) {
        float4 f0 = { o0, o1, o2, o3 }, f1 = { o4, o5, o6, o7 };
        *reinterpret_cast<float4*>(of + (size_t)row * 2048 + tid * 8) = f0;
        *reinterpret_cast<float4*>(of + (size_t)row * 2048 + tid * 8 + 4) = f1;
    }
}

// ---------------------------------------------------------------- generic GEMM
// C[r][c] = sum_k A[r][k] * W[c][k]  (+ resid), A:(Mx K) f16, W:(N x K) f16.
__global__ __launch_bounds__(256) void k_gemm(
    const _Float16* __restrict__ A, int lda,
    const _Float16* __restrict__ W, int ldw,
    float* __restrict__ C, int ldc,
    const float* __restrict__ resid, int K)
{
    __shared__ __align__(16) _Float16 As[128][40];
    __shared__ __align__(16) _Float16 Ws[128][40];
    const int r0 = blockIdx.x * 128, c0 = blockIdx.y * 128;
    const int tid = threadIdx.x, lane = tid & 63, wid = tid >> 6;
    const int wr = wid >> 1, wc = wid & 1;
    const int srow = tid >> 2, scol = (tid & 3) * 8;
    const int fr = lane & 15, fk = (lane >> 4) * 8;
    const f32x4 z4 = { 0.f, 0.f, 0.f, 0.f };
    f32x4 acc[4][4];
    #pragma unroll
    for (int i = 0; i < 4; i++)
        #pragma unroll
        for (int j = 0; j < 4; j++) acc[i][j] = z4;

    for (int k0 = 0; k0 < K; k0 += 32) {
        *reinterpret_cast<int4*>(&As[srow][scol]) =
            *reinterpret_cast<const int4*>(A + (size_t)(r0 + srow) * lda + k0 + scol);
        *reinterpret_cast<int4*>(&As[srow + 64][scol]) =
            *reinterpret_cast<const int4*>(A + (size_t)(r0 + srow + 64) * lda + k0 + scol);
        *reinterpret_cast<int4*>(&Ws[srow][scol]) =
            *reinterpret_cast<const int4*>(W + (size_t)(c0 + srow) * ldw + k0 + scol);
        *reinterpret_cast<int4*>(&Ws[srow + 64][scol]) =
            *reinterpret_cast<const int4*>(W + (size_t)(c0 + srow + 64) * ldw + k0 + scol);
        __syncthreads();
        f16x8 af[4], bf[4];
        #pragma unroll
        for (int i = 0; i < 4; i++)
            af[i] = *reinterpret_cast<const f16x8*>(&As[wr * 64 + i * 16 + fr][fk]);
        #pragma unroll
        for (int j = 0; j < 4; j++)
            bf[j] = *reinterpret_cast<const f16x8*>(&Ws[wc * 64 + j * 16 + fr][fk]);
        #pragma unroll
        for (int i = 0; i < 4; i++)
            #pragma unroll
            for (int j = 0; j < 4; j++)
                acc[i][j] = __builtin_amdgcn_mfma_f32_16x16x32_f16(af[i], bf[j], acc[i][j], 0, 0, 0);
        __syncthreads();
    }
    #pragma unroll
    for (int i = 0; i < 4; i++) {
        const int rowb = r0 + wr * 64 + i * 16 + (lane >> 4) * 4;
        #pragma unroll
        for (int j = 0; j < 4; j++) {
            const int col = c0 + wc * 64 + j * 16 + fr;
            #pragma unroll
            for (int r = 0; r < 4; r++) {
                size_t idx = (size_t)(rowb + r) * ldc + col;
                float v = acc[i][j][r];
                if (resid) v += resid[idx];
                C[idx] = v;
            }
        }
    }
}

// ------------------------------------------- per-head RMSNorm + RoPE + V-transpose
// grid (4096 tokens, 40): u<32 -> q head, u<36 -> k head, else v head. block=128
__global__ __launch_bounds__(128) void k_qkv_post(
    const float* __restrict__ qf, const float* __restrict__ kf, const float* __restrict__ vf,
    const float* __restrict__ cosb, const float* __restrict__ sinb,
    const float* __restrict__ qn_w, const float* __restrict__ kn_w,
    _Float16* __restrict__ qh, _Float16* __restrict__ kh, _Float16* __restrict__ vth)
{
    const int tok = blockIdx.x, u = blockIdx.y, d = threadIdx.x;
    const int b = tok >> 10, l = tok & 1023;
    __shared__ float buf[128];
    __shared__ float r2[2];
    if (u < 32) {
        float val = qf[(size_t)tok * 4096 + u * 128 + d];
        float ss = val * val;
        #pragma unroll
        for (int m = 1; m < 64; m <<= 1) ss += __shfl_xor(ss, m);
        if ((d & 63) == 0) r2[d >> 6] = ss;
        __syncthreads();
        float rms = rsqrtf((r2[0] + r2[1]) * (1.f / 128.f) + 1e-6f);
        float nv = val * rms * qn_w[d];
        buf[d] = nv;
        __syncthreads();
        float rot = (d < 64) ? -buf[d + 64] : buf[d - 64];
        float o = cosb[(size_t)tok * 128 + d] * nv + sinb[(size_t)tok * 128 + d] * rot;
        qh[(size_t)tok * 4096 + u * 128 + d] = (_Float16)o;
    } else if (u < 36) {
        int kv = u - 32;
        float val = kf[(size_t)tok * 512 + kv * 128 + d];
        float ss = val * val;
        #pragma unroll
        for (int m = 1; m < 64; m <<= 1) ss += __shfl_xor(ss, m);
        if ((d & 63) == 0) r2[d >> 6] = ss;
        __syncthreads();
        float rms = rsqrtf((r2[0] + r2[1]) * (1.f / 128.f) + 1e-6f);
        float nv = val * rms * kn_w[d];
        buf[d] = nv;
        __syncthreads();
        float rot = (d < 64) ? -buf[d + 64] : buf[d - 64];
        float o = cosb[(size_t)tok * 128 + d] * nv + sinb[(size_t)tok * 128 + d] * rot;
        kh[(((size_t)b * 4 + kv) * 1024 + l) * 128 + d] = (_Float16)o;
    } else {
        int kv = u - 36;
        float val = vf[(size_t)tok * 512 + kv * 128 + d];
        vth[(((size_t)b * 4 + kv) * 128 + d) * 1024 + l] = (_Float16)val;
    }
}

// ---------------------------------------------------------------- attention
// grid (64 q-tiles of 16 rows, B*H=128). block=256 (4 waves); wave w owns keys
// [w*256, w*256+256). Full-row softmax, unnormalized PV, epilogue divides.
__global__ __launch_bounds__(256) void k_attn(
    const _Float16* __restrict__ qh, const _Float16* __restrict__ kh,
    const _Float16* __restrict__ vth, _Float16* __restrict__ oh)
{
    const int qt = blockIdx.x, bh = blockIdx.y;
    const int b = bh >> 5, h = bh & 31, kv = h >> 3;
    const int q0 = qt * 16;
    const int tid = threadIdx.x, lane = tid & 63, wid = tid >> 6;
    __shared__ __align__(16) _Float16 Qs[16][136];
    __shared__ __align__(16) _Float16 Ps[16][1032];   // aliased as O-reduction later
    __shared__ float Mred[16][4];
    __shared__ float Sred[16][4];

    {   // load Q tile
        int r = tid >> 4, c = (tid & 15) * 8;
        *reinterpret_cast<int4*>(&Qs[r][c]) =
            *reinterpret_cast<const int4*>(qh + ((size_t)(b * 1024 + q0 + r)) * 4096 + h * 128 + c);
    }
    __syncthreads();

    const int fr = lane & 15, fg = lane >> 4;
    const int key0 = wid * 256;
    const bool active = (key0 <= q0 + 15);
    const f32x4 z4 = { 0.f, 0.f, 0.f, 0.f };
    f32x4 sc[16];
    #pragma unroll
    for (int j = 0; j < 16; j++) sc[j] = z4;

    if (active) {
        f16x8 aq[4];
        #pragma unroll
        for (int kk = 0; kk < 4; kk++)
            aq[kk] = *reinterpret_cast<const f16x8*>(&Qs[fr][kk * 32 + fg * 8]);
        const _Float16* kb = kh + ((size_t)(b * 4 + kv)) * 1024 * 128;
        #pragma unroll
        for (int j = 0; j < 16; j++) {
            const _Float16* krow = kb + (size_t)(key0 + j * 16 + fr) * 128;
            #pragma unroll
            for (int kk = 0; kk < 4; kk++) {
                f16x8 bk = *reinterpret_cast<const f16x8*>(krow + kk * 32 + fg * 8);
                sc[j] = __builtin_amdgcn_mfma_f32_16x16x32_f16(aq[kk], bk, sc[j], 0, 0, 0);
            }
        }
    }

    float rmax[4] = { -3e38f, -3e38f, -3e38f, -3e38f };
    if (active) {
        #pragma unroll
        for (int j = 0; j < 16; j++) {
            int key = key0 + j * 16 + fr;
            #pragma unroll
            for (int r = 0; r < 4; r++) {
                int qrow = q0 + fg * 4 + r;
                float v = sc[j][r] * 0.08838834764831845f;
                if (key > qrow) v = -1e30f;
                sc[j][r] = v;
                rmax[r] = fmaxf(rmax[r], v);
            }
        }
        #pragma unroll
        for (int m = 1; m < 16; m <<= 1)
            #pragma unroll
            for (int r = 0; r < 4; r++) rmax[r] = fmaxf(rmax[r], __shfl_xor(rmax[r], m));
    }
    if (fr == 0) {
        #pragma unroll
        for (int r = 0; r < 4; r++) Mred[fg * 4 + r][wid] = rmax[r];
    }
    __syncthreads();
    float gmax[4];
    #pragma unroll
    for (int r = 0; r < 4; r++) {
        int row = fg * 4 + r;
        gmax[r] = fmaxf(fmaxf(Mred[row][0], Mred[row][1]), fmaxf(Mred[row][2], Mred[row][3]));
    }
    float rsum[4] = { 0.f, 0.f, 0.f, 0.f };
    if (active) {
        #pragma unroll
        for (int j = 0; j < 16; j++)
            #pragma unroll
            for (int r = 0; r < 4; r++) {
                float p = __expf(sc[j][r] - gmax[r]);
                sc[j][r] = p;
                rsum[r] += p;
            }
        #pragma unroll
        for (int m = 1; m < 16; m <<= 1)
            #pragma unroll
            for (int r = 0; r < 4; r++) rsum[r] += __shfl_xor(rsum[r], m);
    }
    if (fr == 0) {
        #pragma unroll
        for (int r = 0; r < 4; r++) Sred[fg * 4 + r][wid] = rsum[r];
    }
    // write P (own chunk only is ever read)
    #pragma unroll
    for (int j = 0; j < 16; j++)
        #pragma unroll
        for (int r = 0; r < 4; r++)
            Ps[fg * 4 + r][key0 + j * 16 + fr] = active ? (_Float16)sc[j][r] : (_Float16)0.f;
    __syncthreads();

    f32x4 oacc[8];
    #pragma unroll
    for (int j = 0; j < 8; j++) oacc[j] = z4;
    if (active) {
        const _Float16* vb = vth + ((size_t)(b * 4 + kv)) * 128 * 1024;
        #pragma unroll
        for (int ks = 0; ks < 8; ks++) {
            f16x8 ap = *reinterpret_cast<const f16x8*>(&Ps[fr][key0 + ks * 32 + fg * 8]);
            #pragma unroll
            for (int dj = 0; dj < 8; dj++) {
                f16x8 bv = *reinterpret_cast<const f16x8*>(
                    vb + (size_t)(dj * 16 + fr) * 1024 + key0 + ks * 32 + fg * 8);
                oacc[dj] = __builtin_amdgcn_mfma_f32_16x16x32_f16(ap, bv, oacc[dj], 0, 0, 0);
            }
        }
    }
    __syncthreads();                     // all Ps reads done -> reuse as float buf
    float* Ored = reinterpret_cast<float*>(&Ps[0][0]);   // 4*16*128 f32 = 32KB
    #pragma unroll
    for (int dj = 0; dj < 8; dj++)
        #pragma unroll
        for (int r = 0; r < 4; r++)
            Ored[((wid * 16) + fg * 4 + r) * 128 + dj * 16 + fr] = oacc[dj][r];
    __syncthreads();
    for (int t = tid; t < 2048; t += 256) {
        int r = t >> 7, d = t & 127;
        float s = Ored[(0 * 16 + r) * 128 + d] + Ored[(1 * 16 + r) * 128 + d]
                + Ored[(2 * 16 + r) * 128 + d] + Ored[(3 * 16 + r) * 128 + d];
        float St = Sred[r][0] + Sred[r][1] + Sred[r][2] + Sred[r][3];
        oh[((size_t)(b * 1024 + q0 + r)) * 4096 + h * 128 + d] = (_Float16)(s / St);
    }
}

// ---------------------------------------------------------------- router
// one wave per token; fp32 logits; exact softmax + top-8 + renorm
__global__ __launch_bounds__(256) void k_router(
    const float* __restrict__ hm, const float* __restrict__ rw,
    float* __restrict__ wdense)
{
    const int tok = blockIdx.x * 4 + (threadIdx.x >> 6);
    const int lane = threadIdx.x & 63;
    __shared__ float lg[4][16];
    const float* hr = hm + (size_t)tok * 2048;
    for (int e = 0; e < 16; e++) {
        float acc = 0.f;
        #pragma unroll
        for (int i = 0; i < 32; i++) acc += hr[i * 64 + lane] * rw[(size_t)e * 2048 + i * 64 + lane];
        #pragma unroll
        for (int m = 1; m < 64; m <<= 1) acc += __shfl_xor(acc, m);
        if (lane == 0) lg[threadIdx.x >> 6][e] = acc;
    }
    __syncthreads();
    if (lane == 0) {
        float* l = lg[threadIdx.x >> 6];
        float mx = l[0];
        for (int e = 1; e < 16; e++) mx = fmaxf(mx, l[e]);
        float p[16]; float sum = 0.f;
        for (int e = 0; e < 16; e++) { p[e] = expf(l[e] - mx); sum += p[e]; }
        for (int e = 0; e < 16; e++) p[e] /= sum;
        bool sel[16]; for (int e = 0; e < 16; e++) sel[e] = false;
        float ssum = 0.f;
        for (int t = 0; t < 8; t++) {
            int bi = -1; float bv = -1.f;
            for (int e = 0; e < 16; e++) if (!sel[e] && p[e] > bv) { bv = p[e]; bi = e; }
            sel[bi] = true; ssum += bv;
        }
        for (int e = 0; e < 16; e++)
            wdense[(size_t)e * 4096 + tok] = sel[e] ? p[e] / ssum : 0.f;
    }
}

// ---------------------------------------------------------------- MoE gate/up (fused SiLU)
// grid (32 token-tiles, 16 experts); out tile 128 tokens x 128 MI
__global__ __launch_bounds__(256) void k_moe_gu(
    const _Float16* __restrict__ hm, const _Float16* __restrict__ gw,
    const _Float16* __restrict__ uw, _Float16* __restrict__ ab)
{
    const int r0 = blockIdx.x * 128, e = blockIdx.y;
    const _Float16* G = gw + (size_t)e * 128 * 2048;
    const _Float16* U = uw + (size_t)e * 128 * 2048;
    __shared__ __align__(16) _Float16 As[128][40];
    __shared__ __align__(16) _Float16 Gs[128][40];
    __shared__ __align__(16) _Float16 Us[128][40];
    const int tid = threadIdx.x, lane = tid & 63, wid = tid >> 6;
    const int wr = wid >> 1, wc = wid & 1;
    const int srow = tid >> 2, scol = (tid & 3) * 8;
    const int fr = lane & 15, fk = (lane >> 4) * 8;
    const f32x4 z4 = { 0.f, 0.f, 0.f, 0.f };
    f32x4 ag[4][4], au[4][4];
    #pragma unroll
    for (int i = 0; i < 4; i++)
        #pragma unroll
        for (int j = 0; j < 4; j++) { ag[i][j] = z4; au[i][j] = z4; }

    for (int k0 = 0; k0 < 2048; k0 += 32) {
        *reinterpret_cast<int4*>(&As[srow][scol]) =
            *reinterpret_cast<const int4*>(hm + (size_t)(r0 + srow) * 2048 + k0 + scol);
        *reinterpret_cast<int4*>(&As[srow + 64][scol]) =
            *reinterpret_cast<const int4*>(hm + (size_t)(r0 + srow + 64) * 2048 + k0 + scol);
        *reinterpret_cast<int4*>(&Gs[srow][scol]) =
            *reinterpret_cast<const int4*>(G + (size_t)srow * 2048 + k0 + scol);
        *reinterpret_cast<int4*>(&Gs[srow + 64][scol]) =
            *reinterpret_cast<const int4*>(G + (size_t)(srow + 64) * 2048 + k0 + scol);
        *reinterpret_cast<int4*>(&Us[srow][scol]) =
            *reinterpret_cast<const int4*>(U + (size_t)srow * 2048 + k0 + scol);
        *reinterpret_cast<int4*>(&Us[srow + 64][scol]) =
            *reinterpret_cast<const int4*>(U + (size_t)(srow + 64) * 2048 + k0 + scol);
        __syncthreads();
        f16x8 af[4], bg[4], bu[4];
        #pragma unroll
        for (int i = 0; i < 4; i++)
            af[i] = *reinterpret_cast<const f16x8*>(&As[wr * 64 + i * 16 + fr][fk]);
        #pragma unroll
        for (int j = 0; j < 4; j++) {
            bg[j] = *reinterpret_cast<const f16x8*>(&Gs[wc * 64 + j * 16 + fr][fk]);
            bu[j] = *reinterpret_cast<const f16x8*>(&Us[wc * 64 + j * 16 + fr][fk]);
        }
        #pragma unroll
        for (int i = 0; i < 4; i++)
            #pragma unroll
            for (int j = 0; j < 4; j++) {
                ag[i][j] = __builtin_amdgcn_mfma_f32_16x16x32_f16(af[i], bg[j], ag[i][j], 0, 0, 0);
                au[i][j] = __builtin_amdgcn_mfma_f32_16x16x32_f16(af[i], bu[j], au[i][j], 0, 0, 0);
            }
        __syncthreads();
    }
    #pragma unroll
    for (int i = 0; i < 4; i++) {
        const int rowb = r0 + wr * 64 + i * 16 + (lane >> 4) * 4;
        #pragma unroll
        for (int j = 0; j < 4; j++) {
            const int col = wc * 64 + j * 16 + fr;
            #pragma unroll
            for (int r = 0; r < 4; r++) {
                float g = ag[i][j][r], uu = au[i][j][r];
                float sil = g / (1.f + __expf(-g));
                ab[((size_t)e * 4096 + rowb + r) * 128 + col] = (_Float16)(sil * uu);
            }
        }
    }
}

// ---------------------------------------------------------------- MoE down + both residuals
// grid (32 token-tiles, 16 dm-tiles); loops all 16 experts, weights per token
__global__ __launch_bounds__(256) void k_moe_down(
    const _Float16* __restrict__ ab, const _Float16* __restrict__ dw,
    const float* __restrict__ wdense, const float* __restrict__ x2,
    float* __restrict__ out)
{
    const int r0 = blockIdx.x * 128, c0 = blockIdx.y * 128;
    __shared__ __align__(16) _Float16 As[128][40];
    __shared__ __align__(16) _Float16 Ws[128][40];
    const int tid = threadIdx.x, lane = tid & 63, wid = tid >> 6;
    const int wr = wid >> 1, wc = wid & 1;
    const int srow = tid >> 2, scol = (tid & 3) * 8;
    const int fr = lane & 15, fk = (lane >> 4) * 8;
    const f32x4 z4 = { 0.f, 0.f, 0.f, 0.f };
    f32x4 acc[4][4];
    #pragma unroll
    for (int i = 0; i < 4; i++)
        #pragma unroll
        for (int j = 0; j < 4; j++) acc[i][j] = z4;

    for (int e = 0; e < 16; e++) {
        const _Float16* A = ab + (size_t)e * 4096 * 128;
        const _Float16* W = dw + (size_t)e * 2048 * 128;
        f32x4 pa[4][4];
        #pragma unroll
        for (int i = 0; i < 4; i++)
            #pragma unroll
            for (int j = 0; j < 4; j++) pa[i][j] = z4;
        for (int k0 = 0; k0 < 128; k0 += 32) {
            *reinterpret_cast<int4*>(&As[srow][scol]) =
                *reinterpret_cast<const int4*>(A + (size_t)(r0 + srow) * 128 + k0 + scol);
            *reinterpret_cast<int4*>(&As[srow + 64][scol]) =
                *reinterpret_cast<const int4*>(A + (size_t)(r0 + srow + 64) * 128 + k0 + scol);
            *reinterpret_cast<int4*>(&Ws[srow][scol]) =
                *reinterpret_cast<const int4*>(W + (size_t)(c0 + srow) * 128 + k0 + scol);
            *reinterpret_cast<int4*>(&Ws[srow + 64][scol]) =
                *reinterpret_cast<const int4*>(W + (size_t)(c0 + srow + 64) * 128 + k0 + scol);
            __syncthreads();
            f16x8 af[4], bf[4];
            #pragma unroll
            for (int i = 0; i < 4; i++)
                af[i] = *reinterpret_cast<const f16x8*>(&As[wr * 64 + i * 16 + fr][fk]);
            #pragma unroll
            for (int j = 0; j < 4; j++)
                bf[j] = *reinterpret_cast<const f16x8*>(&Ws[wc * 64 + j * 16 + fr][fk]);
            #pragma unroll
            for (int i = 0; i < 4; i++)
                #pragma unroll
                for (int j = 0; j < 4; j++)
                    pa[i][j] = __builtin_amdgcn_mfma_f32_16x16x32_f16(af[i], bf[j], pa[i][j], 0, 0, 0);
            __syncthreads();
        }
        #pragma unroll
        for (int i = 0; i < 4; i++) {
            const int rowb = r0 + wr * 64 + i * 16 + (lane >> 4) * 4;
            float wv[4];
            #pragma unroll
            for (int r = 0; r < 4; r++) wv[r] = wdense[(size_t)e * 4096 + rowb + r];
            #pragma unroll
            for (int j = 0; j < 4; j++)
                #pragma unroll
                for (int r = 0; r < 4; r++) acc[i][j][r] += wv[r] * pa[i][j][r];
        }
    }
    #pragma unroll
    for (int i = 0; i < 4; i++) {
        const int rowb = r0 + wr * 64 + i * 16 + (lane >> 4) * 4;
        #pragma unroll
        for (int j = 0; j < 4; j++) {
            const int col = c0 + wc * 64 + j * 16 + fr;
            #pragma unroll
            for (int r = 0; r < 4; r++) {
                size_t idx = (size_t)(rowb + r) * 2048 + col;
                out[idx] = x2[idx] + acc[i][j][r];
            }
        }
    }
}

// ---------------------------------------------------------------- launch

extern "C" void kernel_launch(void* const* d_in, const int* in_sizes, int n_in,
                              void* d_out, int out_size, void* d_ws, size_t ws_size,
                              hipStream_t stream)
{
    const float* x        = (const float*)d_in[0];
    const float* cosb     = (const float*)d_in[1];
    const float* sinb     = (const float*)d_in[2];
    const float* nattn    = (const float*)d_in[3];
    const float* q_w      = (const float*)d_in[4];
    const float* k_w      = (const float*)d_in[5];
    const float* v_w      = (const float*)d_in[6];
    const float* qn_w     = (const float*)d_in[7];
    const float* kn_w     = (const float*)d_in[8];
    const float* o_w      = (const float*)d_in[9];
    const float* nmlp     = (const float*)d_in[10];
    const float* router_w = (const float*)d_in[11];
    const float* egw      = (const float*)d_in[12];
    const float* euw      = (const float*)d_in[13];
    const float* edw      = (const float*)d_in[14];

    char* w = (char*)d_ws;
    // persistent fp16 weights
    _Float16* qw_h = (_Float16*)(w + 0);           // 16.78 MB
    _Float16* kw_h = (_Float16*)(w + 16777216);    //  2.10 MB
    _Float16* vw_h = (_Float16*)(w + 18874368);    //  2.10 MB
    _Float16* ow_h = (_Float16*)(w + 20971520);    // 16.78 MB
    _Float16* gw_h = (_Float16*)(w + 37748736);    //  8.39 MB
    _Float16* uw_h = (_Float16*)(w + 46137344);    //  8.39 MB
    _Float16* dw_h = (_Float16*)(w + 54525952);    //  8.39 MB
    _Float16* h_h  = (_Float16*)(w + 62914560);    // 16.78 MB (reused as ab later)
    _Float16* ab_h = h_h;
    // region R: q_f32/k_f32/v_f32, later overlaid by o_h / x2 / hm_h
    float*    q_f  = (float*)(w + 79691776);       // 67.11 MB
    float*    k_f  = (float*)(w + 146800640);      //  8.39 MB
    float*    v_f  = (float*)(w + 155189248);      //  8.39 MB
    _Float16* o_h  = (_Float16*)(w + 79691776);    // 33.55 MB (overlay q_f low)
    float*    x2   = (float*)(w + 113246208);      // 33.55 MB (overlay q_f high)
    _Float16* hm_h = (_Float16*)(w + 146800640);   // 16.78 MB (overlay k_f/v_f)
    _Float16* q_h  = (_Float16*)(w + 163577856);   // 33.55 MB
    float*    hm_f = (float*)(w + 163577856);      // overlay q_h after attention
    _Float16* k_h  = (_Float16*)(w + 197132288);   //  4.19 MB
    _Float16* vt_h = (_Float16*)(w + 201326592);   //  4.19 MB
    float*    wdense = (float*)(w + 205520896);    //  0.26 MB   (total ~196 MB)

    // 1. weight casts
    k_cast<<<8192, 256, 0, stream>>>(q_w, qw_h, 8388608);
    k_cast<<<1024, 256, 0, stream>>>(k_w, kw_h, 1048576);
    k_cast<<<1024, 256, 0, stream>>>(v_w, vw_h, 1048576);
    k_cast<<<8192, 256, 0, stream>>>(o_w, ow_h, 8388608);
    k_cast<<<4096, 256, 0, stream>>>(egw, gw_h, 4194304);
    k_cast<<<4096, 256, 0, stream>>>(euw, uw_h, 4194304);
    k_cast<<<4096, 256, 0, stream>>>(edw, dw_h, 4194304);
    // 2. attn rmsnorm
    k_rmsnorm<<<4096, 256, 0, stream>>>(x, nattn, h_h, nullptr);
    // 3. QKV projections
    k_gemm<<<dim3(32, 32), 256, 0, stream>>>(h_h, 2048, qw_h, 2048, q_f, 4096, nullptr, 2048);
    k_gemm<<<dim3(32, 4),  256, 0, stream>>>(h_h, 2048, kw_h, 2048, k_f, 512,  nullptr, 2048);
    k_gemm<<<dim3(32, 4),  256, 0, stream>>>(h_h, 2048, vw_h, 2048, v_f, 512,  nullptr, 2048);
    // 4. qk-norm + rope + v transpose
    k_qkv_post<<<dim3(4096, 40), 128, 0, stream>>>(q_f, k_f, v_f, cosb, sinb, qn_w, kn_w,
                                                   q_h, k_h, vt_h);
    // 5. attention
    k_attn<<<dim3(64, 128), 256, 0, stream>>>(q_h, k_h, vt_h, o_h);
    // 6. O projection + residual
    k_gemm<<<dim3(32, 16), 256, 0, stream>>>(o_h, 4096, ow_h, 4096, x2, 2048, x, 4096);
    // 7. mlp rmsnorm (f16 + f32)
    k_rmsnorm<<<4096, 256, 0, stream>>>(x2, nmlp, hm_h, hm_f);
    // 8. router
    k_router<<<1024, 256, 0, stream>>>(hm_f, router_w, wdense);
    // 9. MoE gate/up + SiLU
    k_moe_gu<<<dim3(32, 16), 256, 0, stream>>>(hm_h, gw_h, uw_h, ab_h);
    // 10. MoE down + residuals -> out
    k_moe_down<<<dim3(32, 16), 256, 0, stream>>>(ab_h, dw_h, wdense, x2, (float*)d_out);

    (void)in_sizes; (void)n_in; (void)out_size; (void)ws_size;
}